// Round 10
// baseline (192.727 us; speedup 1.0000x reference)
//
#include <hip/hip_runtime.h>

#define Bb 2
#define Tt 2048
#define Cc_ 1024
#define Hh 16
#define HDd 64

typedef __attribute__((ext_vector_type(8))) short bf16x8;
typedef __attribute__((ext_vector_type(4))) float f32x4;
typedef __attribute__((ext_vector_type(16))) float f32x16;
typedef __attribute__((ext_vector_type(4))) unsigned short u16x4;
typedef __attribute__((ext_vector_type(2))) unsigned int u32x2;

__device__ __forceinline__ unsigned short f2bf(float f) {
  union { float f; unsigned int u; } v; v.f = f;
  unsigned int r = v.u + 0x7FFFu + ((v.u >> 16) & 1u);
  return (unsigned short)(r >> 16);
}
__device__ __forceinline__ float bf2f(unsigned short u) {
  union { unsigned int u; float f; } v; v.u = ((unsigned int)u) << 16;
  return v.f;
}
__device__ __forceinline__ unsigned int cvtpk(float lo, float hi) {
  unsigned int r;
  asm("v_cvt_pk_bf16_f32 %0, %1, %2" : "=v"(r) : "v"(lo), "v"(hi));
  return r;
}
__device__ __forceinline__ f32x4 mfma16(bf16x8 a, bf16x8 b, f32x4 c) {
  return __builtin_amdgcn_mfma_f32_16x16x32_bf16(a, b, c, 0, 0, 0);
}
__device__ __forceinline__ f32x16 mfma32(bf16x8 a, bf16x8 b, f32x16 c) {
  return __builtin_amdgcn_mfma_f32_32x32x16_bf16(a, b, c, 0, 0, 0);
}
__device__ __forceinline__ void gl_lds16(const void* g, void* l) {
  auto* gp = reinterpret_cast<const __attribute__((address_space(1))) unsigned int*>(
      reinterpret_cast<unsigned long long>(g));
  auto* lp = reinterpret_cast<__attribute__((address_space(3))) unsigned int*>(
      reinterpret_cast<unsigned long long>(l));
  __builtin_amdgcn_global_load_lds(gp, lp, 16, 0, 0);
}

// ---------------- fused prep: x->bf16 | Wqkv -> permuted-transposed bf16 | Wproj^T ----------------
__global__ __launch_bounds__(256) void k_prep(const float* __restrict__ x,
                                              const float* __restrict__ Wqkv,
                                              const float* __restrict__ Wproj,
                                              unsigned short* __restrict__ xb,
                                              unsigned short* __restrict__ wqkvt,
                                              unsigned short* __restrict__ wprot) {
  const int bid = blockIdx.x;
  const int tid = threadIdx.x;
  if (bid < 4096) {  // x convert
    const int i = bid * 256 + tid;
    f32x4 v = ((const f32x4*)x)[i];
    u16x4 o;
    o[0] = f2bf(v[0]); o[1] = f2bf(v[1]); o[2] = f2bf(v[2]); o[3] = f2bf(v[3]);
    ((u16x4*)xb)[i] = o;
    return;
  }
  __shared__ float tile[32][33];
  const int tx = tid & 31, ty = tid >> 5;  // (32, 8)
  if (bid < 4096 + 3072) {  // Wqkv permuted transpose: out[3072][1024]
    const int tt = bid - 4096;
    const int n0 = (tt % 96) * 32, k0 = (tt / 96) * 32;
    const int region = n0 >> 10, nl = n0 & 1023;
    const int ob = (nl >> 6) * 192 + region * 64 + (nl & 63);
#pragma unroll
    for (int i = 0; i < 4; ++i)
      tile[ty + i * 8][tx] = Wqkv[(size_t)(k0 + ty + i * 8) * 3072 + ob + tx];
    __syncthreads();
#pragma unroll
    for (int i = 0; i < 4; ++i)
      wqkvt[(size_t)(n0 + ty + i * 8) * 1024 + k0 + tx] = f2bf(tile[tx][ty + i * 8]);
    return;
  }
  // Wproj transpose: out[1024][1024]
  const int tt = bid - 7168;
  const int c0 = (tt & 31) * 32, r0 = (tt >> 5) * 32;
#pragma unroll
  for (int i = 0; i < 4; ++i)
    tile[ty + i * 8][tx] = Wproj[(size_t)(r0 + ty + i * 8) * 1024 + c0 + tx];
  __syncthreads();
#pragma unroll
  for (int i = 0; i < 4; ++i)
    wprot[(size_t)(c0 + ty + i * 8) * 1024 + r0 + tx] = f2bf(tile[tx][ty + i * 8]);
}

// ---------------- GEMM1 (qkv): dbuf prefetch main loop, fused RoPE + V-transpose epilogue ------
__global__ __launch_bounds__(256) void k_gemm_qkv(const unsigned short* __restrict__ A,
                                                  const unsigned short* __restrict__ Bt,
                                                  const float* __restrict__ rsin,
                                                  const float* __restrict__ rcos,
                                                  unsigned short* __restrict__ Qo,
                                                  unsigned short* __restrict__ Ko,
                                                  unsigned short* __restrict__ Vt) {
  __shared__ unsigned short lA[2][128 * 64];
  __shared__ unsigned short lB[2][128 * 64];
  const int K = 1024;
  const int tid = threadIdx.x;
  const int lane = tid & 63, wid = tid >> 6;
  const int wr = wid >> 1, wc = wid & 1;
  const int bm = blockIdx.y * 128, bn = blockIdx.x * 128;
  const int l15 = lane & 15, l4 = lane >> 4;
  f32x4 acc[4][4];
#pragma unroll
  for (int i = 0; i < 4; ++i)
#pragma unroll
    for (int j = 0; j < 4; ++j) acc[i][j] = f32x4{0.f, 0.f, 0.f, 0.f};

#define STG(BUF, TT)                                                        \
  {                                                                         \
    const int k0 = (TT) << 6;                                               \
    _Pragma("unroll") for (int i = 0; i < 4; ++i) {                         \
      const int slot = i * 256 + tid;                                       \
      const int row = slot >> 3, g = slot & 7;                              \
      const int gs = (g ^ (row & 7)) * 8;                                   \
      gl_lds16(A + (size_t)(bm + row) * K + k0 + gs, &lA[BUF][slot * 8]);   \
      gl_lds16(Bt + (size_t)(bn + row) * K + k0 + gs, &lB[BUF][slot * 8]);  \
    }                                                                       \
  }

  STG(0, 0);
  asm volatile("s_waitcnt vmcnt(0)" ::: "memory");
  __builtin_amdgcn_s_barrier();
  for (int t = 0; t < 16; ++t) {
    const int cur = t & 1;
    if (t + 1 < 16) STG(cur ^ 1, t + 1);
    __builtin_amdgcn_s_setprio(1);
#pragma unroll
    for (int ks = 0; ks < 2; ++ks) {
      bf16x8 af[4], bfr[4];
#pragma unroll
      for (int mf = 0; mf < 4; ++mf) {
        const int row = wr * 64 + mf * 16 + l15;
        const int g = ks * 4 + l4;
        af[mf] = *(const bf16x8*)&lA[cur][row * 64 + ((g ^ (row & 7)) * 8)];
      }
#pragma unroll
      for (int nf = 0; nf < 4; ++nf) {
        const int row = wc * 64 + nf * 16 + l15;
        const int g = ks * 4 + l4;
        bfr[nf] = *(const bf16x8*)&lB[cur][row * 64 + ((g ^ (row & 7)) * 8)];
      }
#pragma unroll
      for (int mf = 0; mf < 4; ++mf)
#pragma unroll
        for (int nf = 0; nf < 4; ++nf)
          acc[mf][nf] = mfma16(af[mf], bfr[nf], acc[mf][nf]);
    }
    __builtin_amdgcn_s_setprio(0);
    if (t + 1 < 16) asm volatile("s_waitcnt vmcnt(0)" ::: "memory");
    __builtin_amdgcn_s_barrier();
  }
#undef STG

  const int rb = bm + wr * 64 + l4 * 4;
  const int region = blockIdx.x >> 3;
  if (region < 2) {  // q or k: rope epilogue (fp32, on accumulators)
    const int h = (blockIdx.x & 7) * 2 + wc;
    unsigned short* dst = (region == 0) ? Qo : Ko;
    const float qs = (region == 0) ? (0.125f * 1.44269504088896f) : 1.0f;
#pragma unroll
    for (int mf = 0; mf < 4; ++mf)
#pragma unroll
      for (int j = 0; j < 4; ++j) {
        const int trow = rb + mf * 16 + j;
        const int bi = trow >> 11, t = trow & 2047;
        const size_t rowb = ((size_t)(bi * Hh + h) * Tt + t) * 64;
#pragma unroll
        for (int nf = 0; nf < 2; ++nf) {
          const int d = nf * 16 + l15;
          const float sn = rsin[t * 32 + d], cs = rcos[t * 32 + d];
          const float a1 = acc[mf][nf][j], a2 = acc[mf][nf + 2][j];
          dst[rowb + d] = f2bf((a1 * cs - a2 * sn) * qs);
          dst[rowb + d + 32] = f2bf((a1 * sn + a2 * cs) * qs);
        }
      }
  } else {  // v: LDS transpose -> Vt [bh][64][T] directly
    unsigned short* tp = &lA[0][0];
    const int h0 = (blockIdx.x & 7) * 2;
    const int bi = bm >> 11, tbase = bm & 2047;
    const int dd = tid >> 2, t0c = (tid & 3) * 32;
#pragma unroll
    for (int ph = 0; ph < 2; ++ph) {
      if (wc == ph) {
#pragma unroll
        for (int mf = 0; mf < 4; ++mf)
#pragma unroll
          for (int nf = 0; nf < 4; ++nf)
#pragma unroll
            for (int j = 0; j < 4; ++j) {
              const int tl = wr * 64 + mf * 16 + l4 * 4 + j;
              const int dl = nf * 16 + l15;
              tp[tl * 65 + dl] = f2bf(acc[mf][nf][j]);
            }
      }
      __syncthreads();
      const size_t ob = ((size_t)(bi * Hh + h0 + ph) * 64 + dd) * (size_t)Tt + tbase + t0c;
#pragma unroll
      for (int c = 0; c < 8; ++c) {
        u16x4 v4;
#pragma unroll
        for (int e = 0; e < 4; ++e) v4[e] = tp[(t0c + c * 4 + e) * 65 + dd];
        *(u16x4*)&Vt[ob + c * 4] = v4;
      }
      __syncthreads();
    }
  }
}

// ---------------- causal flash attention: 32x32 MFMA, in-register P ----------------
// 1024 blocks x 128 thr (2 waves x 32 q-rows = QBLK 64). Same XCD/balance decode as r5.
// Swapped QK via mfma32(K,Q): lane holds 32 scores of q-row (lane&31) -> 31 fmax + 1 shfl.
// P stays in registers: cvt_pk pairs + 8 shfl_xor(32) feed PV A-frags (no lP LDS).
// K/V dbuf 32KB, 4 blocks/CU. Defer-max (T13); alpha/linv redistributed via 32-float
// per-wave LDS scratch (rare path / epilogue only).
__global__ __launch_bounds__(128, 2) void k_attn(const unsigned short* __restrict__ Q,
                                                 const unsigned short* __restrict__ Kt,
                                                 const unsigned short* __restrict__ Vt,
                                                 unsigned short* __restrict__ Aout) {
  __shared__ unsigned short lK[2 * 64 * 64];
  __shared__ unsigned short lV[2 * 64 * 64];
  __shared__ float sred[2][32];
  const int bid = blockIdx.x;
  const int xcd = bid & 7, ss = bid >> 3;
  const int cc = ss & 31, kk = ss >> 5;
  const int bh = xcd * 4 + kk;
  const int c2 = (cc + ((kk & 2) ? 16 : 0)) & 31;
  const int qt = (kk & 1) ? (31 - c2) : c2;
  const int b = bh >> 4, h = bh & 15;
  const int tid = threadIdx.x, lane = tid & 63, w = tid >> 6;  // w in {0,1}
  const int l31 = lane & 31, ht = lane >> 5, l7 = lane & 7;
  const int qb = qt * 64;
  const unsigned short* Kbh = Kt + (size_t)bh * Tt * 64;
  const unsigned short* Vbh = Vt + (size_t)bh * 64 * Tt;

  // fragment element offsets: off[chunk][g4]: row = chunk*32+l31, granule = ht+g4*2, XOR-swz
  int off[2][4];
#pragma unroll
  for (int c = 0; c < 2; ++c)
#pragma unroll
    for (int g4 = 0; g4 < 4; ++g4)
      off[c][g4] = (c * 32 + l31) * 64 + (((ht + g4 * 2) ^ l7) * 8);
  // staging: 8 x gl_lds16/thread (4 K rows + 4 V rows), linear dest + inv-swz source
  const int rA = tid >> 3, gA = tid & 7;
  const int sws = (gA ^ (rA & 7)) * 8;

#define STAGE(BUF, TT)                                                              \
  {                                                                                 \
    const int kv_ = (TT) * 64;                                                      \
    _Pragma("unroll") for (int i = 0; i < 4; ++i) {                                 \
      const int row = rA + i * 16;                                                  \
      gl_lds16(Kbh + (size_t)(kv_ + row) * 64 + sws, &lK[(BUF)*4096 + row * 64 + gA * 8]); \
      gl_lds16(Vbh + (size_t)row * 2048 + kv_ + sws, &lV[(BUF)*4096 + row * 64 + gA * 8]); \
    }                                                                               \
  }

  // Q B-frags: lane col = qrow (l31), k-dim d = kd*16 + ht*8
  const size_t qrow_off = ((size_t)bh * Tt + qb + w * 32 + l31) * 64;
  bf16x8 qf[4];
#pragma unroll
  for (int kd = 0; kd < 4; ++kd) qf[kd] = *(const bf16x8*)&Q[qrow_off + kd * 16 + ht * 8];

  f32x16 o0, o1;
#pragma unroll
  for (int r = 0; r < 16; ++r) { o0[r] = 0.f; o1[r] = 0.f; }
  float mrun = -1e30f, lrun = 0.f;  // q-row (l31) stats, log2 domain; lrun per-lane partial
  const int nt = qt + 1;

#define BODY(CUR, T, LASTT)                                                             \
  {                                                                                     \
    if ((T) + 1 < nt) STAGE(CUR ^ 1, (T) + 1);                                          \
    f32x16 s0, s1;                                                                      \
    _Pragma("unroll") for (int r = 0; r < 16; ++r) { s0[r] = 0.f; s1[r] = 0.f; }        \
    __builtin_amdgcn_s_setprio(1);                                                      \
    _Pragma("unroll") for (int kd = 0; kd < 4; ++kd) {                                  \
      const bf16x8 k0 = *(const bf16x8*)&lK[(CUR)*4096 + off[0][kd]];                   \
      const bf16x8 k1 = *(const bf16x8*)&lK[(CUR)*4096 + off[1][kd]];                   \
      s0 = mfma32(k0, qf[kd], s0);                                                      \
      s1 = mfma32(k1, qf[kd], s1);                                                      \
    }                                                                                   \
    __builtin_amdgcn_s_setprio(0);                                                      \
    if (LASTT) {                                                                        \
      const int qr = w * 32 + l31;                                                      \
      _Pragma("unroll") for (int r = 0; r < 16; ++r) {                                  \
        const int key0 = (r & 3) + 8 * (r >> 2) + 4 * ht;                               \
        if (key0 > qr) s0[r] = -3e38f;                                                  \
        if (32 + key0 > qr) s1[r] = -3e38f;                                             \
      }                                                                                 \
    }                                                                                   \
    float mx = fmaxf(s0[0], s1[0]);                                                     \
    _Pragma("unroll") for (int r = 1; r < 16; ++r) mx = fmaxf(mx, fmaxf(s0[r], s1[r])); \
    mx = fmaxf(mx, __shfl_xor(mx, 32, 64));                                             \
    if (!__all(mx - mrun <= 8.0f)) {                                                    \
      const float mnew = fmaxf(mrun, mx);                                               \
      const float alpha = exp2f(mrun - mnew);                                           \
      lrun *= alpha;                                                                    \
      if (lane < 32) sred[w][l31] = alpha;                                              \
      _Pragma("unroll") for (int r = 0; r < 16; ++r) {                                  \
        const float av = sred[w][(r & 3) + 8 * (r >> 2) + 4 * ht];                      \
        o0[r] *= av; o1[r] *= av;                                                       \
      }                                                                                 \
      mrun = mnew;                                                                      \
    }                                                                                   \
    float ssum = 0.f;                                                                   \
    _Pragma("unroll") for (int r = 0; r < 16; ++r) {                                    \
      const float p0 = exp2f(s0[r] - mrun), p1 = exp2f(s1[r] - mrun);                   \
      ssum += p0 + p1; s0[r] = p0; s1[r] = p1;                                          \
    }                                                                                   \
    lrun += ssum;                                                                       \
    unsigned int u0[8], u1[8];                                                          \
    _Pragma("unroll") for (int rr = 0; rr < 8; ++rr) {                                  \
      u0[rr] = cvtpk(s0[2 * rr], s0[2 * rr + 1]);                                       \
      u1[rr] = cvtpk(s1[2 * rr], s1[2 * rr + 1]);                                       \
    }                                                                                   \
    unsigned int rc0[4], rc1[4];                                                        \
    _Pragma("unroll") for (int jj = 0; jj < 4; ++jj) {                                  \
      const int a = (jj >> 1) * 4 + (jj & 1);                                           \
      rc0[jj] = __shfl_xor((int)(ht ? u0[a] : u0[a + 2]), 32, 64);                      \
      rc1[jj] = __shfl_xor((int)(ht ? u1[a] : u1[a + 2]), 32, 64);                      \
    }                                                                                   \
    __builtin_amdgcn_s_setprio(1);                                                      \
    _Pragma("unroll") for (int ks = 0; ks < 4; ++ks) {                                  \
      const int b4 = (ks & 1) * 4, b2 = (ks & 1) * 2;                                   \
      union { unsigned int u[4]; bf16x8 v; } pa;                                        \
      if (ks < 2) {                                                                     \
        pa.u[0] = ht ? rc0[b2] : u0[b4];                                                \
        pa.u[1] = ht ? rc0[b2 + 1] : u0[b4 + 1];                                        \
        pa.u[2] = ht ? u0[b4 + 2] : rc0[b2];                                            \
        pa.u[3] = ht ? u0[b4 + 3] : rc0[b2 + 1];                                        \
      } else {                                                                          \
        pa.u[0] = ht ? rc1[b2] : u1[b4];                                                \
        pa.u[1] = ht ? rc1[b2 + 1] : u1[b4 + 1];                                        \
        pa.u[2] = ht ? u1[b4 + 2] : rc1[b2];                                            \
        pa.u[3] = ht ? u1[b4 + 3] : rc1[b2 + 1];                                        \
      }                                                                                 \
      const bf16x8 vb0 = *(const bf16x8*)&lV[(CUR)*4096 + off[0][ks]];                  \
      const bf16x8 vb1 = *(const bf16x8*)&lV[(CUR)*4096 + off[1][ks]];                  \
      o0 = mfma32(pa.v, vb0, o0);                                                       \
      o1 = mfma32(pa.v, vb1, o1);                                                       \
    }                                                                                   \
    __builtin_amdgcn_s_setprio(0);                                                      \
    if ((T) + 1 < nt) asm volatile("s_waitcnt vmcnt(0)" ::: "memory");                  \
    __builtin_amdgcn_s_barrier();                                                       \
  }

  STAGE(0, 0);
  asm volatile("s_waitcnt vmcnt(0)" ::: "memory");
  __builtin_amdgcn_s_barrier();
  int t = 0;
  for (; t + 2 < nt; t += 2) {
    BODY(0, t, false);
    BODY(1, t + 1, false);
  }
  if (nt - t == 2) {
    BODY(0, t, false);
    BODY(1, t + 1, true);
  } else {
    BODY(0, t, true);
  }
#undef BODY
#undef STAGE

  lrun += __shfl_xor(lrun, 32, 64);
  if (lane < 32) sred[w][l31] = 1.f / lrun;
  const size_t outb = (size_t)(b * Tt + qb + w * 32) * 1024 + h * 64;
#pragma unroll
  for (int r = 0; r < 16; ++r) {
    const int q = (r & 3) + 8 * (r >> 2) + 4 * ht;
    const float li = sred[w][q];
    Aout[outb + (size_t)q * 1024 + l31] = f2bf(o0[r] * li);
    Aout[outb + (size_t)q * 1024 + 32 + l31] = f2bf(o1[r] * li);
  }
}

// ---------------- GEMM2: attn [4096][1024] x wprot -> out fp32, dbuf prefetch ----------------
__global__ __launch_bounds__(256) void k_gemm2(const unsigned short* __restrict__ A,
                                               const unsigned short* __restrict__ Bt,
                                               float* __restrict__ Cout) {
  __shared__ unsigned short lA[2][128 * 64];
  __shared__ unsigned short lB[2][64 * 64];
  const int K = 1024, N = 1024;
  const int tid = threadIdx.x;
  const int lane = tid & 63, w = tid >> 6;
  const int bm = blockIdx.y * 128, bn = blockIdx.x * 64;
  const int l15 = lane & 15, l4 = lane >> 4;
  f32x4 acc[2][4];
#pragma unroll
  for (int i = 0; i < 2; ++i)
#pragma unroll
    for (int j = 0; j < 4; ++j) acc[i][j] = f32x4{0.f, 0.f, 0.f, 0.f};

#define STG(BUF, TT)                                                        \
  {                                                                         \
    const int k0 = (TT) << 6;                                               \
    _Pragma("unroll") for (int i = 0; i < 4; ++i) {                         \
      const int slot = i * 256 + tid;                                       \
      const int row = slot >> 3, g = slot & 7;                              \
      const int gs = (g ^ (row & 7)) * 8;                                   \
      gl_lds16(A + (size_t)(bm + row) * K + k0 + gs, &lA[BUF][slot * 8]);   \
    }                                                                       \
    _Pragma("unroll") for (int i = 0; i < 2; ++i) {                         \
      const int slot = i * 256 + tid;                                       \
      const int row = slot >> 3, g = slot & 7;                              \
      const int gs = (g ^ (row & 7)) * 8;                                   \
      gl_lds16(Bt + (size_t)(bn + row) * K + k0 + gs, &lB[BUF][slot * 8]);  \
    }                                                                       \
  }

  STG(0, 0);
  asm volatile("s_waitcnt vmcnt(0)" ::: "memory");
  __builtin_amdgcn_s_barrier();
  for (int t = 0; t < 16; ++t) {
    const int cur = t & 1;
    if (t + 1 < 16) STG(cur ^ 1, t + 1);
    __builtin_amdgcn_s_setprio(1);
#pragma unroll
    for (int ks = 0; ks < 2; ++ks) {
      bf16x8 af[2], bfr[4];
#pragma unroll
      for (int mf = 0; mf < 2; ++mf) {
        const int row = w * 32 + mf * 16 + l15;
        const int g = ks * 4 + l4;
        af[mf] = *(const bf16x8*)&lA[cur][row * 64 + ((g ^ (row & 7)) * 8)];
      }
#pragma unroll
      for (int nf = 0; nf < 4; ++nf) {
        const int row = nf * 16 + l15;
        const int g = ks * 4 + l4;
        bfr[nf] = *(const bf16x8*)&lB[cur][row * 64 + ((g ^ (row & 7)) * 8)];
      }
#pragma unroll
      for (int mf = 0; mf < 2; ++mf)
#pragma unroll
        for (int nf = 0; nf < 4; ++nf)
          acc[mf][nf] = mfma16(af[mf], bfr[nf], acc[mf][nf]);
    }
    __builtin_amdgcn_s_setprio(0);
    if (t + 1 < 16) asm volatile("s_waitcnt vmcnt(0)" ::: "memory");
    __builtin_amdgcn_s_barrier();
  }
#undef STG
  const int rb = bm + w * 32 + l4 * 4;
  const int cb = bn + l15;
#pragma unroll
  for (int mf = 0; mf < 2; ++mf)
#pragma unroll
    for (int nf = 0; nf < 4; ++nf)
#pragma unroll
      for (int j = 0; j < 4; ++j)
        Cout[(size_t)(rb + mf * 16 + j) * N + cb + nf * 16] = acc[mf][nf][j];
}

extern "C" void kernel_launch(void* const* d_in, const int* in_sizes, int n_in,
                              void* d_out, int out_size, void* d_ws, size_t ws_size,
                              hipStream_t stream) {
  const float* x = (const float*)d_in[0];
  const float* Wqkv = (const float*)d_in[1];
  const float* Wproj = (const float*)d_in[2];
  const float* rsin = (const float*)d_in[3];
  const float* rcos = (const float*)d_in[4];
  float* out = (float*)d_out;
  char* ws = (char*)d_ws;
  unsigned short* xb = (unsigned short*)(ws);
  unsigned short* wqkvt = (unsigned short*)(ws + (size_t)(8 << 20));
  unsigned short* wprot = (unsigned short*)(ws + (size_t)(14 << 20));
  unsigned short* Q = (unsigned short*)(ws + (size_t)(40 << 20));
  unsigned short* K = (unsigned short*)(ws + (size_t)(48 << 20));
  unsigned short* Vt = (unsigned short*)(ws + (size_t)(56 << 20));
  unsigned short* attn = (unsigned short*)(ws + (size_t)(64 << 20));

  k_prep<<<8192, 256, 0, stream>>>(x, Wqkv, Wproj, xb, wqkvt, wprot);
  k_gemm_qkv<<<dim3(24, 32), 256, 0, stream>>>(xb, wqkvt, rsin, rcos, Q, K, Vt);
  k_attn<<<1024, 128, 0, stream>>>(Q, K, Vt, attn);
  k_gemm2<<<dim3(16, 32), 256, 0, stream>>>(attn, wprot, out);
}